// Round 4
// baseline (571.646 us; speedup 1.0000x reference)
//
#include <hip/hip_runtime.h>

#define VXC 0.2f
#define VYC 0.2f
#define XMINC -51.2f
#define YMINC -51.2f
#define GXD 512
#define GYD 512
#define NVOXD (GXD * GYD)   // 2^18
#define BN_EPS 1e-3f
#define NBLK 1024           // persistent grid: 4 blocks/CU x 256 CUs

// K0: zero off[n] + barrier counters (int4/thread) and, in the extra last
// block, fold BN into the linear layer (P layout [9][64]).
__global__ void init_and_precompute(int* __restrict__ cnt, int nzero4,
                                    const float* __restrict__ W,
                                    const float* __restrict__ gamma,
                                    const float* __restrict__ beta,
                                    const float* __restrict__ mean,
                                    const float* __restrict__ var,
                                    float* __restrict__ P) {
    int nzero_blocks = (nzero4 + 255) / 256;
    if ((int)blockIdx.x < nzero_blocks) {
        int i = blockIdx.x * 256 + threadIdx.x;
        if (i < nzero4) ((int4*)cnt)[i] = make_int4(0, 0, 0, 0);
        return;
    }
    int c = threadIdx.x;
    if (c >= 64) return;
    float scale = gamma[c] * (1.0f / sqrtf(var[c] + BN_EPS));
    float w0 = W[0*64+c], w1 = W[1*64+c], w2 = W[2*64+c];
    float w3 = W[3*64+c], w4 = W[4*64+c], w5 = W[5*64+c];
    float w6 = W[6*64+c], w7 = W[7*64+c], w8 = W[8*64+c];
    P[0*64+c] = (w0 + w3 + w6) * scale;
    P[1*64+c] = (w1 + w4 + w7) * scale;
    P[2*64+c] = (w2 + w5 + w8) * scale;
    P[3*64+c] = w3 * scale;
    P[4*64+c] = w4 * scale;
    P[5*64+c] = w5 * scale;
    P[6*64+c] = w6 * scale;
    P[7*64+c] = w7 * scale;
    P[8*64+c] = beta[c] - mean[c] * scale;
}

// Grid barrier (cg::grid::sync mechanism): release add makes this block's
// plain stores device-visible (agent REL -> wbl2); acquire load after the
// spin invalidates stale L2 lines (agent ACQ -> inv). Counter pre-zeroed.
__device__ __forceinline__ void gbar(int* bar) {
    __syncthreads();
    if (threadIdx.x == 0) {
        __hip_atomic_fetch_add(bar, 1, __ATOMIC_RELEASE, __HIP_MEMORY_SCOPE_AGENT);
        while (__hip_atomic_load(bar, __ATOMIC_RELAXED, __HIP_MEMORY_SCOPE_AGENT) < NBLK)
            __builtin_amdgcn_s_sleep(2);
        int x = __hip_atomic_load(bar, __ATOMIC_ACQUIRE, __HIP_MEMORY_SCOPE_AGENT);
        (void)x;
    }
    __syncthreads();
}

// MEGA: bin -> chunk scan -> base scan -> scatter -> gather, one dispatch.
// Points + packed (bin,pos) records held in REGISTERS from bin to scatter.
__global__ __launch_bounds__(256, 4)
void mega(const float* __restrict__ pc0, const float* __restrict__ pc1,
          int* __restrict__ off, int* __restrict__ bar,
          int* __restrict__ bsums, int* __restrict__ aux,
          float4* __restrict__ csr, const float* __restrict__ P,
          float* __restrict__ out, int B, int N, int npts, int n) {
    int tid = threadIdx.x;
    int gi = blockIdx.x * 256 + tid;
    int nq2 = npts >> 2;             // 100000 quads
    int per4 = (B * N) >> 2;         // 50000 quads per cloud

    // ---- phase A: bin (atomics on off[] used as counts) ----
    float4 q0, q1, q2; unsigned r[4];
    bool active = gi < nq2;
    if (active) {
        int cloud = (gi >= per4) ? 1 : 0;
        int i2 = gi - cloud * per4;
        int b = i2 / (N >> 2);       // N % 4 == 0
        const float4* p4 = (const float4*)(cloud ? pc1 : pc0) + (size_t)i2 * 3;
        q0 = p4[0]; q1 = p4[1]; q2 = p4[2];
        float xs[4] = {q0.x, q0.w, q1.z, q2.y};
        float ys[4] = {q0.y, q1.x, q1.w, q2.z};
        int vbase = (cloud * B + b) * NVOXD;
        #pragma unroll
        for (int k = 0; k < 4; ++k) {
            // Bit-exact with reference binning
            int ix = (int)floorf((xs[k] - XMINC) / VXC); ix = min(max(ix, 0), GXD - 1);
            int iy = (int)floorf((ys[k] - YMINC) / VYC); iy = min(max(iy, 0), GYD - 1);
            int hidx = vbase + ix * GYD + iy;
            int pos = atomicAdd(off + hidx, 1);
            r[k] = ((unsigned)hidx << 8) | (unsigned)pos;   // pos < 256
        }
    }
    gbar(bar + 0);

    // ---- phase B: each block scans its 1024-entry chunk in place ----
    __shared__ int lds[256];
    {
        size_t base = (size_t)blockIdx.x * 1024 + (size_t)tid * 4;
        int4 v = *(const int4*)(off + base);
        int t0 = v.x, t1 = t0 + v.y, t2 = t1 + v.z, t3 = t2 + v.w;
        lds[tid] = t3;
        __syncthreads();
        for (int d = 1; d < 256; d <<= 1) {
            int t = (tid >= d) ? lds[tid - d] : 0;
            __syncthreads();
            lds[tid] += t;
            __syncthreads();
        }
        int excl = lds[tid] - t3;
        if (tid == 255) bsums[blockIdx.x] = lds[255];
        *(int4*)(off + base) = make_int4(excl, excl + t0, excl + t1, excl + t2);
    }
    gbar(bar + 1);

    // ---- phase C: block 0 exclusive-scans the 1024 chunk sums -> aux ----
    if (blockIdx.x == 0) {
        int4 v = *(const int4*)(bsums + tid * 4);
        int t0 = v.x, t1 = t0 + v.y, t2 = t1 + v.z, t3 = t2 + v.w;
        lds[tid] = t3;
        __syncthreads();
        for (int d = 1; d < 256; d <<= 1) {
            int t = (tid >= d) ? lds[tid - d] : 0;
            __syncthreads();
            lds[tid] += t;
            __syncthreads();
        }
        int excl = lds[tid] - t3;
        *(int4*)(aux + tid * 4) = make_int4(excl, excl + t0, excl + t1, excl + t2);
    }
    gbar(bar + 2);

    // ---- phase D: scatter from registers (global off = off + aux[chunk]) ----
    if (active) {
        float xs[4] = {q0.x, q0.w, q1.z, q2.y};
        float ys[4] = {q0.y, q1.x, q1.w, q2.z};
        float zs[4] = {q0.z, q1.y, q2.x, q2.w};
        #pragma unroll
        for (int k = 0; k < 4; ++k) {
            int bin = (int)(r[k] >> 8);
            int o = off[bin] + aux[bin >> 10] + (int)(r[k] & 255u);
            csr[o] = make_float4(xs[k], ys[k], zs[k], 0.0f);
        }
    }
    gbar(bar + 3);

    // ---- phase E: gather (grid-stride, wave per 8 voxels, lane=channel) ----
    int c = tid & 63;
    float A   = P[0*64+c], Bw  = P[1*64+c], Cw  = P[2*64+c];
    float w3s = P[3*64+c], w4s = P[4*64+c], w5s = P[5*64+c];
    float w6s = P[6*64+c], w7s = P[7*64+c], offc = P[8*64+c];
    float A1 = A - w3s, B1 = Bw - w4s, C1 = Cw - w5s;   // 1-point fast path
    int base1 = B * NVOXD;           // 524288
    int noct = base1 >> 3;           // 65536 octo-groups
    int gw = gi >> 6;                // global wave id (4096 waves)

    for (int w = gw; w < noct; w += NBLK * 4) {
        int bv0 = w << 3;
        int4 a0  = *(const int4*)(off + bv0);
        int4 a0b = *(const int4*)(off + bv0 + 4);
        int4 a1  = *(const int4*)(off + base1 + bv0);
        int4 a1b = *(const int4*)(off + base1 + bv0 + 4);
        int r0[9] = {a0.x, a0.y, a0.z, a0.w, a0b.x, a0b.y, a0b.z, a0b.w,
                     off[bv0 + 8]};
        int idx1_last = base1 + bv0 + 8;
        int r1[9] = {a1.x, a1.y, a1.z, a1.w, a1b.x, a1b.y, a1b.z, a1b.w,
                     (idx1_last < n) ? off[idx1_last] : 0};
        int f0[9], f1[9];
        #pragma unroll
        for (int k = 0; k < 9; ++k) {
            f0[k] = r0[k] + aux[(bv0 + k) >> 10];
            int idx1 = base1 + bv0 + k;
            f1[k] = (idx1 == n) ? npts : r1[k] + aux[idx1 >> 10];
        }
        #pragma unroll
        for (int q = 0; q < 8; ++q) {
            int bv = bv0 + q;
            int s0 = f0[q], e0 = f0[q + 1];
            int s1 = f1[q], e1 = f1[q + 1];
            float res = 0.0f;
            if (e0 > s0 || e1 > s1) {            // wave-uniform branch
                int v = bv & (NVOXD - 1);
                int ix = v >> 9, iy = v & 511;
                float cx = ((float)ix + 0.5f) * VXC + XMINC;
                float cy = ((float)iy + 0.5f) * VYC + YMINC;
                float basef = offc - cx * w6s - cy * w7s;
                int n0 = e0 - s0;
                if (n0 == 1) {
                    float4 pt = csr[s0];
                    res -= fmaxf(pt.x * A1 + pt.y * B1 + pt.z * C1 + basef, 0.0f);
                } else if (n0 > 1) {
                    float sx = 0.0f, sy = 0.0f, sz = 0.0f;
                    for (int j = s0; j < e0; ++j) {
                        float4 pt = csr[j];
                        sx += pt.x; sy += pt.y; sz += pt.z;
                    }
                    float inv = 1.0f / (float)n0;
                    float cbias = basef - (sx * w3s + sy * w4s + sz * w5s) * inv;
                    float hsum = 0.0f;
                    for (int j = s0; j < e0; ++j) {     // L1-hot re-read
                        float4 pt = csr[j];
                        hsum += fmaxf(pt.x * A + pt.y * Bw + pt.z * Cw + cbias, 0.0f);
                    }
                    res -= hsum * inv;
                }
                int n1 = e1 - s1;
                if (n1 == 1) {
                    float4 pt = csr[s1];
                    res += fmaxf(pt.x * A1 + pt.y * B1 + pt.z * C1 + basef, 0.0f);
                } else if (n1 > 1) {
                    float sx = 0.0f, sy = 0.0f, sz = 0.0f;
                    for (int j = s1; j < e1; ++j) {
                        float4 pt = csr[j];
                        sx += pt.x; sy += pt.y; sz += pt.z;
                    }
                    float inv = 1.0f / (float)n1;
                    float cbias = basef - (sx * w3s + sy * w4s + sz * w5s) * inv;
                    float hsum = 0.0f;
                    for (int j = s1; j < e1; ++j) {
                        float4 pt = csr[j];
                        hsum += fmaxf(pt.x * A + pt.y * Bw + pt.z * Cw + cbias, 0.0f);
                    }
                    res += hsum * inv;
                }
            }
            __builtin_nontemporal_store(res, out + ((size_t)bv << 6) + c);
        }
    }
}

extern "C" void kernel_launch(void* const* d_in, const int* in_sizes, int n_in,
                              void* d_out, int out_size, void* d_ws, size_t ws_size,
                              hipStream_t stream) {
    const float* pc0   = (const float*)d_in[0];
    const float* pc1   = (const float*)d_in[1];
    const float* Wm    = (const float*)d_in[2];
    const float* gamma = (const float*)d_in[3];
    const float* beta  = (const float*)d_in[4];
    const float* mean  = (const float*)d_in[5];
    const float* var   = (const float*)d_in[6];
    float* out = (float*)d_out;

    int B = out_size / (NVOXD * 64);        // = 2
    int N = in_sizes[0] / (3 * B);          // = 100000
    int npts = 2 * B * N;                   // 400000
    int n = 2 * B * NVOXD;                  // 2^20 bins

    // ws layout (16B aligned): csr | off[n+4] | bar[8] | bsums | aux | P
    float4* csr   = (float4*)d_ws;
    int* off      = (int*)(csr + npts + 4);
    int* bar      = off + n + 4;
    int* bsums    = bar + 8;
    int* aux      = bsums + NBLK;
    float* P      = (float*)(aux + NBLK);

    // zero off[n+4] + bar[8] = n+12 ints = n/4+3 int4s
    int nzero4 = n / 4 + 3;
    int nzero_blocks = (nzero4 + 255) / 256;
    init_and_precompute<<<nzero_blocks + 1, 256, 0, stream>>>(
        off, nzero4, Wm, gamma, beta, mean, var, P);

    mega<<<NBLK, 256, 0, stream>>>(pc0, pc1, off, bar, bsums, aux, csr, P, out,
                                   B, N, npts, n);
}

// Round 6
// 225.767 us; speedup vs baseline: 2.5320x; 2.5320x over previous
//
#include <hip/hip_runtime.h>

#define VXC 0.2f
#define VYC 0.2f
#define XMINC -51.2f
#define YMINC -51.2f
#define GXD 512
#define GYD 512
#define NVOXD (GXD * GYD)   // 2^18
#define BN_EPS 1e-3f

typedef float vfloat4 __attribute__((ext_vector_type(4)));   // native clang vector

// K0: zero the 4 MB count array (int4/thread, blocks [0, nzero)) and, in the
// extra last block, fold BN into the linear layer (P layout [9][64]).
__global__ void init_and_precompute(int* __restrict__ cnt, int nzero4,
                                    const float* __restrict__ W,
                                    const float* __restrict__ gamma,
                                    const float* __restrict__ beta,
                                    const float* __restrict__ mean,
                                    const float* __restrict__ var,
                                    float* __restrict__ P) {
    int nzero_blocks = (nzero4 + 255) / 256;
    if ((int)blockIdx.x < nzero_blocks) {
        int i = blockIdx.x * 256 + threadIdx.x;
        if (i < nzero4) ((int4*)cnt)[i] = make_int4(0, 0, 0, 0);
        return;
    }
    int c = threadIdx.x;
    if (c >= 64) return;
    float scale = gamma[c] * (1.0f / sqrtf(var[c] + BN_EPS));
    float w0 = W[0*64+c], w1 = W[1*64+c], w2 = W[2*64+c];
    float w3 = W[3*64+c], w4 = W[4*64+c], w5 = W[5*64+c];
    float w6 = W[6*64+c], w7 = W[7*64+c], w8 = W[8*64+c];
    P[0*64+c] = (w0 + w3 + w6) * scale;
    P[1*64+c] = (w1 + w4 + w7) * scale;
    P[2*64+c] = (w2 + w5 + w8) * scale;
    P[3*64+c] = w3 * scale;
    P[4*64+c] = w4 * scale;
    P[5*64+c] = w5 * scale;
    P[6*64+c] = w6 * scale;
    P[7*64+c] = w7 * scale;
    P[8*64+c] = beta[c] - mean[c] * scale;
}

// K1: 4 points per thread via 3x float4 loads; one scattered atomic per point;
// pack (vid, pos) into one uint; uint4 store of the 4 packed records.
__global__ void bin_points(const float* __restrict__ pc0, const float* __restrict__ pc1,
                           int* __restrict__ cnt, uint4* __restrict__ pk4,
                           int B, int N) {
    int i = blockIdx.x * blockDim.x + threadIdx.x;
    int per4 = (B * N) >> 2;                 // point-quads per cloud
    if (i >= 2 * per4) return;
    int cloud = (i >= per4) ? 1 : 0;
    int i2 = i - cloud * per4;               // quad id within cloud
    int b = i2 / (N >> 2);                   // N % 4 == 0 -> b uniform over the quad
    const float4* p4 = (const float4*)(cloud ? pc1 : pc0) + (size_t)i2 * 3;
    float4 q0 = p4[0], q1 = p4[1], q2 = p4[2];
    float xs[4] = {q0.x, q0.w, q1.z, q2.y};
    float ys[4] = {q0.y, q1.x, q1.w, q2.z};
    int vbase = (cloud * B + b) * NVOXD;
    unsigned r[4];
    #pragma unroll
    for (int k = 0; k < 4; ++k) {
        // Bit-exact with reference binning
        int ix = (int)floorf((xs[k] - XMINC) / VXC); ix = min(max(ix, 0), GXD - 1);
        int iy = (int)floorf((ys[k] - YMINC) / VYC); iy = min(max(iy, 0), GYD - 1);
        int hidx = vbase + ix * GYD + iy;
        int pos = atomicAdd(cnt + hidx, 1);
        r[k] = ((unsigned)hidx << 8) | (unsigned)pos;   // pos < 256 (lambda=0.38)
    }
    pk4[i] = make_uint4(r[0], r[1], r[2], r[3]);
}

// K2a: block-wise exclusive scan, in place. 256 threads * int4 = 1024 elems/block.
// K2b: same kernel, 1 block over the 1024 block sums -> exclusive chunk bases.
__global__ void scan_block(const int* __restrict__ in, int* __restrict__ out,
                           int* __restrict__ bsums) {
    int tid = threadIdx.x;
    size_t base = (size_t)blockIdx.x * 1024;
    int4 v = ((const int4*)(in + base))[tid];
    int t0 = v.x, t1 = t0 + v.y, t2 = t1 + v.z, t3 = t2 + v.w;
    __shared__ int lds[256];
    lds[tid] = t3;
    __syncthreads();
    for (int d = 1; d < 256; d <<= 1) {
        int t = (tid >= d) ? lds[tid - d] : 0;
        __syncthreads();
        lds[tid] += t;
        __syncthreads();
    }
    int excl = lds[tid] - t3;
    if (tid == 255) bsums[blockIdx.x] = lds[255];
    ((int4*)(out + base))[tid] = make_int4(excl, excl + t0, excl + t1, excl + t2);
}

// K3: 4 points/thread; scattered plain float4 stores (no atomic) into CSR order.
// Global offset = off[bin] (chunk-local) + bsums[bin>>10] (chunk base, 4KB L1-hot).
__global__ void scatter_csr(const float* __restrict__ pc0, const float* __restrict__ pc1,
                            const int* __restrict__ off, const int* __restrict__ bases,
                            const uint4* __restrict__ pk4, float4* __restrict__ csr,
                            int B, int N) {
    int i = blockIdx.x * blockDim.x + threadIdx.x;
    int per4 = (B * N) >> 2;
    if (i >= 2 * per4) return;
    int cloud = (i >= per4) ? 1 : 0;
    int i2 = i - cloud * per4;
    const float4* p4 = (const float4*)(cloud ? pc1 : pc0) + (size_t)i2 * 3;
    float4 q0 = p4[0], q1 = p4[1], q2 = p4[2];
    uint4 pkv = pk4[i];
    float xs[4] = {q0.x, q0.w, q1.z, q2.y};
    float ys[4] = {q0.y, q1.x, q1.w, q2.z};
    float zs[4] = {q0.z, q1.y, q2.x, q2.w};
    unsigned pr[4] = {pkv.x, pkv.y, pkv.z, pkv.w};
    #pragma unroll
    for (int k = 0; k < 4; ++k) {
        int bin = (int)(pr[k] >> 8);
        int o = off[bin] + bases[bin >> 10] + (int)(pr[k] & 255u);
        csr[o] = make_float4(xs[k], ys[k], zs[k], 0.0f);
    }
}

// K4: wave per 8 voxels in 2 steps of 4; quarter-wave per voxel, 4 channels
// per lane -> vfloat4 nontemporal stores (16 B/lane, 1 KB/instruction).
// Cluster stats inline; 1-point fast path collapses to one FMA chain.
__global__ __launch_bounds__(256)
void gather(const float4* __restrict__ csr, const int* __restrict__ off,
            const int* __restrict__ bases, const float* __restrict__ P,
            float* __restrict__ out, int B, int n, int npts) {
    int g = blockIdx.x * blockDim.x + threadIdx.x;
    int lane = g & 63;
    int w = g >> 6;
    int noct = (B * NVOXD) >> 3;
    if (w >= noct) return;
    int sub = lane >> 4;                 // 0..3: voxel within the quartet
    int ch = (lane & 15) << 2;           // channel group base

    float A[4], Bw[4], Cw[4], w3s[4], w4s[4], w5s[4], w6s[4], w7s[4], offc[4];
    #pragma unroll
    for (int k = 0; k < 4; ++k) {
        A[k]    = P[0*64+ch+k]; Bw[k]  = P[1*64+ch+k]; Cw[k]  = P[2*64+ch+k];
        w3s[k]  = P[3*64+ch+k]; w4s[k] = P[4*64+ch+k]; w5s[k] = P[5*64+ch+k];
        w6s[k]  = P[6*64+ch+k]; w7s[k] = P[7*64+ch+k]; offc[k]= P[8*64+ch+k];
    }
    int base1 = B * NVOXD;

    #pragma unroll
    for (int s = 0; s < 2; ++s) {
        int bv = (w << 3) + s * 4 + sub;
        int i0 = bv, i0e = bv + 1;           // i0e <= base1 < n always
        int i1 = base1 + bv, i1e = i1 + 1;   // i1e can be == n
        int s0 = off[i0]  + bases[i0 >> 10];
        int e0 = off[i0e] + bases[i0e >> 10];
        int s1 = off[i1]  + bases[i1 >> 10];
        int e1 = (i1e == n) ? npts : off[i1e] + bases[i1e >> 10];
        float r[4] = {0.0f, 0.0f, 0.0f, 0.0f};
        int n0 = e0 - s0, n1 = e1 - s1;
        if (n0 > 0 || n1 > 0) {              // quarter-wave divergent
            int v = bv & (NVOXD - 1);
            float cx = ((float)(v >> 9) + 0.5f) * VXC + XMINC;
            float cy = ((float)(v & 511) + 0.5f) * VYC + YMINC;
            float bf[4];
            #pragma unroll
            for (int k = 0; k < 4; ++k) bf[k] = offc[k] - cx * w6s[k] - cy * w7s[k];
            // cloud 0 (subtract)
            if (n0 == 1) {
                float4 pt = csr[s0];
                #pragma unroll
                for (int k = 0; k < 4; ++k)
                    r[k] -= fmaxf(pt.x * (A[k] - w3s[k]) + pt.y * (Bw[k] - w4s[k])
                                  + pt.z * (Cw[k] - w5s[k]) + bf[k], 0.0f);
            } else if (n0 > 1) {
                float sx = 0.0f, sy = 0.0f, sz = 0.0f;
                for (int j = s0; j < e0; ++j) {
                    float4 pt = csr[j];
                    sx += pt.x; sy += pt.y; sz += pt.z;
                }
                float inv = 1.0f / (float)n0;
                float cb[4], h[4] = {0.0f, 0.0f, 0.0f, 0.0f};
                #pragma unroll
                for (int k = 0; k < 4; ++k)
                    cb[k] = bf[k] - (sx * w3s[k] + sy * w4s[k] + sz * w5s[k]) * inv;
                for (int j = s0; j < e0; ++j) {      // L1-hot re-read
                    float4 pt = csr[j];
                    #pragma unroll
                    for (int k = 0; k < 4; ++k)
                        h[k] += fmaxf(pt.x * A[k] + pt.y * Bw[k] + pt.z * Cw[k] + cb[k], 0.0f);
                }
                #pragma unroll
                for (int k = 0; k < 4; ++k) r[k] -= h[k] * inv;
            }
            // cloud 1 (add)
            if (n1 == 1) {
                float4 pt = csr[s1];
                #pragma unroll
                for (int k = 0; k < 4; ++k)
                    r[k] += fmaxf(pt.x * (A[k] - w3s[k]) + pt.y * (Bw[k] - w4s[k])
                                  + pt.z * (Cw[k] - w5s[k]) + bf[k], 0.0f);
            } else if (n1 > 1) {
                float sx = 0.0f, sy = 0.0f, sz = 0.0f;
                for (int j = s1; j < e1; ++j) {
                    float4 pt = csr[j];
                    sx += pt.x; sy += pt.y; sz += pt.z;
                }
                float inv = 1.0f / (float)n1;
                float cb[4], h[4] = {0.0f, 0.0f, 0.0f, 0.0f};
                #pragma unroll
                for (int k = 0; k < 4; ++k)
                    cb[k] = bf[k] - (sx * w3s[k] + sy * w4s[k] + sz * w5s[k]) * inv;
                for (int j = s1; j < e1; ++j) {
                    float4 pt = csr[j];
                    #pragma unroll
                    for (int k = 0; k < 4; ++k)
                        h[k] += fmaxf(pt.x * A[k] + pt.y * Bw[k] + pt.z * Cw[k] + cb[k], 0.0f);
                }
                #pragma unroll
                for (int k = 0; k < 4; ++k) r[k] += h[k] * inv;
            }
        }
        vfloat4 v4 = {r[0], r[1], r[2], r[3]};
        __builtin_nontemporal_store(v4, (vfloat4*)(out + ((size_t)bv << 6) + ch));
    }
}

extern "C" void kernel_launch(void* const* d_in, const int* in_sizes, int n_in,
                              void* d_out, int out_size, void* d_ws, size_t ws_size,
                              hipStream_t stream) {
    const float* pc0   = (const float*)d_in[0];
    const float* pc1   = (const float*)d_in[1];
    const float* Wm    = (const float*)d_in[2];
    const float* gamma = (const float*)d_in[3];
    const float* beta  = (const float*)d_in[4];
    const float* mean  = (const float*)d_in[5];
    const float* var   = (const float*)d_in[6];
    float* out = (float*)d_out;

    int B = out_size / (NVOXD * 64);        // = 2
    int N = in_sizes[0] / (3 * B);          // = 100000
    int npts = 2 * B * N;                   // 400000
    int n = 2 * B * NVOXD;                  // 2^20 bins
    int nblocks_scan = n / 1024;            // 1024

    // ws layout (16B aligned): csr | off[n] | bsums[1024] | scratch[4] | pk | P
    float4* csr   = (float4*)d_ws;
    int* off      = (int*)(csr + npts + 4);
    int* bsums    = off + n;
    int* scratch  = bsums + nblocks_scan;
    unsigned* pk  = (unsigned*)(scratch + 4);
    float* P      = (float*)(pk + npts);

    int nzero4 = n / 4;                      // int4s to zero (counts only)
    int nzero_blocks = (nzero4 + 255) / 256;
    init_and_precompute<<<nzero_blocks + 1, 256, 0, stream>>>(
        off, nzero4, Wm, gamma, beta, mean, var, P);

    int nq = npts / 4;                       // 100000 point-quads
    int g1 = (nq + 255) / 256;
    bin_points<<<g1, 256, 0, stream>>>(pc0, pc1, off, (uint4*)pk, B, N);

    scan_block<<<nblocks_scan, 256, 0, stream>>>(off, off, bsums);
    scan_block<<<1, 256, 0, stream>>>(bsums, bsums, scratch);

    scatter_csr<<<g1, 256, 0, stream>>>(pc0, pc1, off, bsums, (const uint4*)pk,
                                        csr, B, N);

    long long total_thr = ((long long)B * NVOXD >> 3) * 64;
    int g2 = (int)((total_thr + 255) / 256);
    gather<<<g2, 256, 0, stream>>>(csr, off, bsums, P, out, B, n, npts);
}